// Round 8
// baseline (2555.696 us; speedup 1.0000x reference)
//
#include <hip/hip_runtime.h>

#define CDIM 64

typedef __attribute__((ext_vector_type(8))) short bf16x8;
typedef __attribute__((ext_vector_type(4))) float f32x4;

// round-to-nearest-even fp32 -> bf16 (as short)
__device__ __forceinline__ short bf16r(float f) {
    unsigned a = __float_as_uint(f);
    a = (a + 0x7fffu + ((a >> 16) & 1u)) >> 16;
    return (short)a;
}
// pack two fp32 as bf16 pair: first -> bits[15:0], second -> bits[31:16]
__device__ __forceinline__ unsigned bfpack(float lo, float hi) {
    unsigned a = __float_as_uint(lo);
    a = (a + 0x7fffu + ((a >> 16) & 1u)) >> 16;
    unsigned b = __float_as_uint(hi);
    b = (b + 0x7fffu + ((b >> 16) & 1u)) & 0xffff0000u;
    return a | b;
}

// --- pack x (fp32) -> bf16 pairs (u32 per 2 channels) ---
__global__ __launch_bounds__(256) void k_pack(const float* __restrict__ x,
                                              unsigned* __restrict__ xb32, size_t n2) {
    size_t t = (size_t)blockIdx.x * 256 + threadIdx.x;
    size_t stride = (size_t)gridDim.x * 256;
    for (size_t i = t; i < n2; i += stride) {
        float2 v = ((const float2*)x)[i];
        xb32[i] = bfpack(v.x, v.y);
    }
}

// ===== R7 restructure: CSR ELIMINATED =====
// Budget closing showed k_part+k_scat2 ~= 105-130us hiding under the top-5
// cutoff since R4 -- pure bookkeeping whose traffic floor is ~6us each.
// k_scat2 existed only to ORDER records per node; but aggregation is a sum,
// order-free. The fused kernel now streams each bucket's UNSORTED records and
// accumulates into an LDS fp32 array (64 nodes x 128ch, bank-padded), degree
// counted in LDS. Deleted: k_scat2, k_bscan, em32, row_start. 9 kernels -> 5.
#define NPB_SHIFT 9                     // 512 nodes per bucket
#define BKN (1 << NPB_SHIFT)
#define BPAD 10240                      // record slots per bucket (mean 8163, sd 90)
#define PART_CH 2048                    // edges per k_part block

// block 0: init padded bucket cursors; blocks 1,2: pre-transpose weights to
// bf16 n-major (wtg[l][m][n][k]) so k_fused reads B-fragments straight from
// global (48KB, L2-broadcast).
__global__ __launch_bounds__(256) void k_prep(int* __restrict__ bkt_cursor, int n_buckets,
                                              const float* __restrict__ w1,
                                              const float* __restrict__ root1,
                                              const float* __restrict__ w2,
                                              const float* __restrict__ root2,
                                              short* __restrict__ wtg) {
    int tid = threadIdx.x;
    if (blockIdx.x == 0) {
        if (tid < n_buckets) bkt_cursor[tid] = tid * BPAD;
        return;
    }
    int l = blockIdx.x - 1;
    const float* s0 = l ? w2 : w1;
    const float* srcs[3] = {s0, s0 + 4096, l ? root2 : root1};
    short* o = wtg + (size_t)l * 3 * 4096;
    for (int i = tid; i < 12288; i += 256) {
        int m = i >> 12, r = i & 4095, k = r >> 6, n = r & 63;  // w row-major [k][n]
        o[(m << 12) + (n << 6) + k] = bf16r(srcs[m][r]);
    }
}

// phase A: bin edges -> bucket-major padded records (d<<32 | s<<15 | u15).
// LDS-staged run writes (R6): records staged bucket-major in LDS, then one
// cooperative sweep emits wave-coalesced bursts per run.
__global__ __launch_bounds__(256) void k_part(const int* __restrict__ src,
                                              const int* __restrict__ dst,
                                              const float* __restrict__ u,
                                              int* __restrict__ bkt_cursor,
                                              unsigned long long* __restrict__ rec,
                                              int n_edges, int n_buckets) {
    __shared__ int cnt_s[256];
    __shared__ int excl_s[256];
    __shared__ int cur_s[256];
    __shared__ int goff_s[256];
    __shared__ int tot_s;
    __shared__ unsigned long long rec_s[PART_CH];   // 16KB
    __shared__ int tgt_s[PART_CH];                  // 8KB
    int tid = threadIdx.x;
    cnt_s[tid] = 0;
    __syncthreads();
    int e0 = blockIdx.x * PART_CH + tid * 8;
    int d[8], s[8];
    float uu[8];
    if (e0 + 8 <= n_edges) {
        int4 d0 = *(const int4*)(dst + e0), d1 = *(const int4*)(dst + e0 + 4);
        int4 s0 = *(const int4*)(src + e0), s1 = *(const int4*)(src + e0 + 4);
        float4 u0 = *(const float4*)(u + e0), u1 = *(const float4*)(u + e0 + 4);
        d[0]=d0.x; d[1]=d0.y; d[2]=d0.z; d[3]=d0.w; d[4]=d1.x; d[5]=d1.y; d[6]=d1.z; d[7]=d1.w;
        s[0]=s0.x; s[1]=s0.y; s[2]=s0.z; s[3]=s0.w; s[4]=s1.x; s[5]=s1.y; s[6]=s1.z; s[7]=s1.w;
        uu[0]=u0.x; uu[1]=u0.y; uu[2]=u0.z; uu[3]=u0.w; uu[4]=u1.x; uu[5]=u1.y; uu[6]=u1.z; uu[7]=u1.w;
    } else {
#pragma unroll
        for (int i = 0; i < 8; ++i) {
            int e = e0 + i;
            bool ok = e < n_edges;
            d[i] = ok ? dst[e] : -1;
            s[i] = ok ? src[e] : 0;
            uu[i] = ok ? u[e] : 0.f;
        }
    }
#pragma unroll
    for (int i = 0; i < 8; ++i)
        if (d[i] >= 0) atomicAdd(&cnt_s[d[i] >> NPB_SHIFT], 1);
    __syncthreads();
    // inclusive scan of bucket counts
    int c = cnt_s[tid];
    excl_s[tid] = c;
    __syncthreads();
    for (int off = 1; off < 256; off <<= 1) {
        int t = (tid >= off) ? excl_s[tid - off] : 0;
        __syncthreads();
        excl_s[tid] += t;
        __syncthreads();
    }
    int excl = excl_s[tid] - c;
    if (tid == 255) tot_s = excl_s[255];
    __syncthreads();
    excl_s[tid] = excl;
    cur_s[tid] = excl;
    goff_s[tid] = (tid < n_buckets && c) ? atomicAdd(&bkt_cursor[tid], c) : 0;
    __syncthreads();
    // handout into staged LDS (bucket-major order) + remember global target
#pragma unroll
    for (int i = 0; i < 8; ++i) {
        if (d[i] >= 0) {
            int b = d[i] >> NPB_SHIFT;
            int p = atomicAdd(&cur_s[b], 1);
            unsigned uq = (unsigned)(uu[i] * 32767.0f + 0.5f);
            rec_s[p] = ((unsigned long long)(unsigned)d[i] << 32)
                     | (unsigned long long)(((unsigned)s[i] << 15) | uq);
            tgt_s[p] = goff_s[b] + (p - excl_s[b]);
        }
    }
    __syncthreads();
    int tot = tot_s;
    for (int i = tid; i < tot; i += 256)
        rec[tgt_s[i]] = rec_s[i];   // consecutive tids -> consecutive targets per run
}

// ===== R7: fused stream-accumulate + GEMM layer kernel =====
// Block = 64 nodes (bucket b, sub-range sub of 8). Streams the bucket's
// ~8163 unsorted records; each QUARTER-wave (16 lanes x uint2 = 64 ch) owns
// one record: gathers the 128B x-row and ds_add_f32's 8 values into the
// node's LDS row. Rows padded to 130 words (bank rotate; stride-128 would be
// an 8-way conflict). Then 8 waves run the MFMA epilogue straight from LDS
// (4 tiles x 2 column-halves). 33.5KB LDS, 512 thr -> 4 blocks/CU = 32
// waves/CU (full) for the latency-bound gather phase.
__global__ __launch_bounds__(512) void k_fused(
        const unsigned* __restrict__ xb_in,   // bf16 rows [n][32] u32 pairs
        const unsigned long long* __restrict__ rec,
        const int* __restrict__ bkt_cursor,
        const short* __restrict__ wb,         // [3][64][64] bf16 (n-major, k-contig)
        const float* __restrict__ bias,
        float* __restrict__ out,              // fp32 out (layer 2) or null
        unsigned short* __restrict__ xb_out,  // bf16 out (layer 1) or null
        int n_nodes) {
    __shared__ float acc[64][130];   // [node][ch]: 0..63 g0, 64..127 g1, +2 pad
    __shared__ int deg[64];
    int tid = threadIdx.x;
    int b = blockIdx.x >> 3;
    int sub = blockIdx.x & 7;
    int lo = (b << NPB_SHIFT) + (sub << 6);   // node range [lo, lo+64)
    int nrec = bkt_cursor[b] - b * BPAD;
    const unsigned long long* r0 = rec + (size_t)b * BPAD;
    const float inv15 = 1.0f / 32767.0f;

    // zero
    for (int i = tid; i < 64 * 130; i += 512) ((float*)acc)[i] = 0.f;
    if (tid < 64) deg[tid] = 0;
    __syncthreads();

    // --- stream-accumulate: quarter-wave per record, stride 32 quarters x4 unroll ---
    int qid = tid >> 4;          // 0..31
    int ql = tid & 15;           // channel-pair group: channels 4ql..4ql+3
    for (int i0 = qid; i0 < nrec; i0 += 128) {
        unsigned long long r[4];
#pragma unroll
        for (int j = 0; j < 4; ++j) {
            int idx = i0 + 32 * j;
            r[j] = (idx < nrec) ? r0[idx] : 0xFFFFFFFF00000000ULL;
        }
        int dd[4]; unsigned em[4]; bool ok[4]; uint2 v[4];
#pragma unroll
        for (int j = 0; j < 4; ++j) {
            dd[j] = (int)(r[j] >> 32) - lo;
            em[j] = (unsigned)r[j];
            ok[j] = (unsigned)dd[j] < 64u;
        }
#pragma unroll
        for (int j = 0; j < 4; ++j)   // issue gathers first (independent, masked)
            if (ok[j]) v[j] = *(const uint2*)(xb_in + (size_t)(em[j] >> 15) * 32 + 2 * ql);
#pragma unroll
        for (int j = 0; j < 4; ++j) {
            if (ok[j]) {
                float uu = (float)(em[j] & 0x7fffu) * inv15;
                float wa = 1.0f - uu;
                float c0 = __uint_as_float(v[j].x << 16);
                float c1 = __uint_as_float(v[j].x & 0xffff0000u);
                float c2 = __uint_as_float(v[j].y << 16);
                float c3 = __uint_as_float(v[j].y & 0xffff0000u);
                int d = dd[j];
                atomicAdd(&acc[d][4 * ql + 0], wa * c0);
                atomicAdd(&acc[d][4 * ql + 1], wa * c1);
                atomicAdd(&acc[d][4 * ql + 2], wa * c2);
                atomicAdd(&acc[d][4 * ql + 3], wa * c3);
                atomicAdd(&acc[d][64 + 4 * ql + 0], uu * c0);
                atomicAdd(&acc[d][64 + 4 * ql + 1], uu * c1);
                atomicAdd(&acc[d][64 + 4 * ql + 2], uu * c2);
                atomicAdd(&acc[d][64 + 4 * ql + 3], uu * c3);
                if (ql == 0) atomicAdd(&deg[d], 1);
            }
        }
    }
    __syncthreads();

    // --- MFMA epilogue (m92-verified layout): 8 waves = 4 tiles x 2 col-halves ---
    int wv = tid >> 6;
    int lane = tid & 63;
    int tile = wv & 3;
    int nthalf = wv >> 2;
    int quad = lane >> 4;
    int m16 = lane & 15;
    int rown = tile * 16 + m16;          // node within block
    int arow = lo + rown;
    bool rowok = arow < n_nodes;
    float s = 1.0f / fmaxf((float)deg[rown], 1.0f);
    const unsigned* xp = xb_in + (size_t)arow * 32;
    bf16x8 zf = {0, 0, 0, 0, 0, 0, 0, 0};
    bf16x8 aG0[2], aG1[2], aX[2];
#pragma unroll
    for (int kf = 0; kf < 2; ++kf) {
        const float* a0 = &acc[rown][kf * 32 + quad * 8];
        const float* a1 = &acc[rown][64 + kf * 32 + quad * 8];
        bf16x8 f0, f1;
#pragma unroll
        for (int j = 0; j < 8; ++j) {
            f0[j] = bf16r(a0[j] * s);
            f1[j] = bf16r(a1[j] * s);
        }
        aG0[kf] = f0;
        aG1[kf] = f1;
        aX[kf] = rowok ? *(const bf16x8*)(xp + kf * 16 + quad * 4) : zf;
    }
#pragma unroll
    for (int nh = 0; nh < 2; ++nh) {
        int nt = nthalf * 2 + nh;
        f32x4 accv = {0.f, 0.f, 0.f, 0.f};
#pragma unroll
        for (int kf = 0; kf < 2; ++kf) {
            int col = nt * 16 + m16;
            bf16x8 bw0 = *(const bf16x8*)(wb + (col << 6) + kf * 32 + quad * 8);
            bf16x8 bw1 = *(const bf16x8*)(wb + ((64 + col) << 6) + kf * 32 + quad * 8);
            bf16x8 bwR = *(const bf16x8*)(wb + ((128 + col) << 6) + kf * 32 + quad * 8);
            accv = __builtin_amdgcn_mfma_f32_16x16x32_bf16(aG0[kf], bw0, accv, 0, 0, 0);
            accv = __builtin_amdgcn_mfma_f32_16x16x32_bf16(aG1[kf], bw1, accv, 0, 0, 0);
            accv = __builtin_amdgcn_mfma_f32_16x16x32_bf16(aX[kf], bwR, accv, 0, 0, 0);
        }
        float bcol = bias[nt * 16 + m16];
#pragma unroll
        for (int r = 0; r < 4; ++r) {
            int node = lo + tile * 16 + quad * 4 + r;
            if (node < n_nodes) {
                size_t off = (size_t)node * CDIM + nt * 16 + m16;
                float o = accv[r] + bcol;
                if (out) out[off] = o;
                if (xb_out) xb_out[off] = (unsigned short)bf16r(o);
            }
        }
    }
}

extern "C" void kernel_launch(void* const* d_in, const int* in_sizes, int n_in,
                              void* d_out, int out_size, void* d_ws, size_t ws_size,
                              hipStream_t stream) {
    const float* x = (const float*)d_in[0];
    const int* edge_index = (const int*)d_in[1];
    const float* edge_attr = (const float*)d_in[2];
    const float* w1 = (const float*)d_in[3];
    const float* root1 = (const float*)d_in[4];
    const float* b1 = (const float*)d_in[5];
    const float* w2 = (const float*)d_in[6];
    const float* root2 = (const float*)d_in[7];
    const float* b2 = (const float*)d_in[8];

    int n_nodes = in_sizes[0] / CDIM;
    int n_edges = in_sizes[2];
    const int* src = edge_index;
    const int* dst = edge_index + n_edges;

    size_t F = (size_t)n_nodes * CDIM;
    int n_buckets = (n_nodes + BKN - 1) >> NPB_SHIFT;   // 196
    unsigned* xbA = (unsigned*)d_ws;              // F/2 u32: bf16(x)
    unsigned* xbB = xbA + F / 2;                  // F/2 u32: bf16(layer-1 out)
    int* bkt_cursor = (int*)(xbB + F / 2);        // n_buckets
    uintptr_t p = (uintptr_t)(bkt_cursor + n_buckets);
    p = (p + 15) & ~(uintptr_t)15;
    short* wtg = (short*)p;                       // [2][3][64][64] bf16
    p += (size_t)2 * 3 * 4096 * sizeof(short);
    p = (p + 15) & ~(uintptr_t)15;
    unsigned long long* rec = (unsigned long long*)p;  // n_buckets*BPAD u64
    float* out = (float*)d_out;

    int gP = (n_edges + PART_CH - 1) / PART_CH;   // 782
    int gF = n_buckets * 8;                       // 1568

    // ---- CSR-free build ----
    k_pack<<<2048, 256, 0, stream>>>(x, xbA, F / 2);
    k_prep<<<3, 256, 0, stream>>>(bkt_cursor, n_buckets, w1, root1, w2, root2, wtg);
    k_part<<<gP, 256, 0, stream>>>(src, dst, edge_attr, bkt_cursor, rec, n_edges, n_buckets);

    // ---- layer 1 (bf16 out only) ----
    k_fused<<<gF, 512, 0, stream>>>(xbA, rec, bkt_cursor, wtg, b1,
                                    nullptr, (unsigned short*)xbB, n_nodes);
    // ---- layer 2 (fp32 out) ----
    k_fused<<<gF, 512, 0, stream>>>(xbB, rec, bkt_cursor, wtg + 3 * 4096, b2,
                                    out, nullptr, n_nodes);
}

// Round 9
// 271.510 us; speedup vs baseline: 9.4129x; 9.4129x over previous
//
#include <hip/hip_runtime.h>

#define CDIM 64

typedef __attribute__((ext_vector_type(8))) short bf16x8;
typedef __attribute__((ext_vector_type(4))) float f32x4;

// round-to-nearest-even fp32 -> bf16 (as short)
__device__ __forceinline__ short bf16r(float f) {
    unsigned a = __float_as_uint(f);
    a = (a + 0x7fffu + ((a >> 16) & 1u)) >> 16;
    return (short)a;
}
// pack two fp32 as bf16 pair: first -> bits[15:0], second -> bits[31:16]
__device__ __forceinline__ unsigned bfpack(float lo, float hi) {
    unsigned a = __float_as_uint(lo);
    a = (a + 0x7fffu + ((a >> 16) & 1u)) >> 16;
    unsigned b = __float_as_uint(hi);
    b = (b + 0x7fffu + ((b >> 16) & 1u)) & 0xffff0000u;
    return a | b;
}

// --- pack x (fp32) -> bf16 pairs (u32 per 2 channels) ---
__global__ __launch_bounds__(256) void k_pack(const float* __restrict__ x,
                                              unsigned* __restrict__ xb32, size_t n2) {
    size_t t = (size_t)blockIdx.x * 256 + threadIdx.x;
    size_t stride = (size_t)gridDim.x * 256;
    for (size_t i = t; i < n2; i += stride) {
        float2 v = ((const float2*)x)[i];
        xb32[i] = bfpack(v.x, v.y);
    }
}

// ===== R8: CSR build folded into the fused kernel =====
// R8 lesson: R7's per-element ds_add_f32 accumulation = ~128 LDS atomics/edge
// -> 1240us (atomic RMW issue-bound; VALU 6.5%, HBM 1.7%). The em32 global
// round-trip deletion was right, the mechanism wrong. Now the fused block
// rebuilds its 64-node mini-CSR IN LDS (stream bucket list once: filter +
// stage + hist -> scan -> ordered place = 2 LDS atomics/edge, off critical
// path) and then runs the PROVEN R5 quarter-wave register aggregation with
// em reads from LDS. k_scat2/k_bscan/em32/row_start stay deleted.
#define NPB_SHIFT 9                     // 512 nodes per bucket
#define BKN (1 << NPB_SHIFT)
#define BPAD 10240                      // record slots per bucket (mean 8163, sd 90)
#define PART_CH 2048                    // edges per k_part block
#define RCAP 1536                       // record slots per 64-node sub-range (mean 1020, sd 32)

// block 0: init padded bucket cursors; blocks 1,2: pre-transpose weights to
// bf16 n-major (wtg[l][m][n][k]) so k_fused reads B-fragments straight from
// global (48KB, L2-broadcast).
__global__ __launch_bounds__(256) void k_prep(int* __restrict__ bkt_cursor, int n_buckets,
                                              const float* __restrict__ w1,
                                              const float* __restrict__ root1,
                                              const float* __restrict__ w2,
                                              const float* __restrict__ root2,
                                              short* __restrict__ wtg) {
    int tid = threadIdx.x;
    if (blockIdx.x == 0) {
        if (tid < n_buckets) bkt_cursor[tid] = tid * BPAD;
        return;
    }
    int l = blockIdx.x - 1;
    const float* s0 = l ? w2 : w1;
    const float* srcs[3] = {s0, s0 + 4096, l ? root2 : root1};
    short* o = wtg + (size_t)l * 3 * 4096;
    for (int i = tid; i < 12288; i += 256) {
        int m = i >> 12, r = i & 4095, k = r >> 6, n = r & 63;  // w row-major [k][n]
        o[(m << 12) + (n << 6) + k] = bf16r(srcs[m][r]);
    }
}

// phase A: bin edges -> bucket-major padded records (d<<32 | s<<15 | u15).
// (R5 version: one-at-a-time handout; the R6 staged variant was part of a
// regressed bundle.)
__global__ __launch_bounds__(256) void k_part(const int* __restrict__ src,
                                              const int* __restrict__ dst,
                                              const float* __restrict__ u,
                                              int* __restrict__ bkt_cursor,
                                              unsigned long long* __restrict__ rec,
                                              int n_edges, int n_buckets) {
    __shared__ int cnt_s[256];
    __shared__ int off_s[256];
    int tid = threadIdx.x;
    cnt_s[tid] = 0;
    __syncthreads();
    int e0 = blockIdx.x * PART_CH + tid * 8;
    int d[8], s[8];
    float uu[8];
    if (e0 + 8 <= n_edges) {
        int4 d0 = *(const int4*)(dst + e0), d1 = *(const int4*)(dst + e0 + 4);
        int4 s0 = *(const int4*)(src + e0), s1 = *(const int4*)(src + e0 + 4);
        float4 u0 = *(const float4*)(u + e0), u1 = *(const float4*)(u + e0 + 4);
        d[0]=d0.x; d[1]=d0.y; d[2]=d0.z; d[3]=d0.w; d[4]=d1.x; d[5]=d1.y; d[6]=d1.z; d[7]=d1.w;
        s[0]=s0.x; s[1]=s0.y; s[2]=s0.z; s[3]=s0.w; s[4]=s1.x; s[5]=s1.y; s[6]=s1.z; s[7]=s1.w;
        uu[0]=u0.x; uu[1]=u0.y; uu[2]=u0.z; uu[3]=u0.w; uu[4]=u1.x; uu[5]=u1.y; uu[6]=u1.z; uu[7]=u1.w;
    } else {
#pragma unroll
        for (int i = 0; i < 8; ++i) {
            int e = e0 + i;
            bool ok = e < n_edges;
            d[i] = ok ? dst[e] : -1;
            s[i] = ok ? src[e] : 0;
            uu[i] = ok ? u[e] : 0.f;
        }
    }
#pragma unroll
    for (int i = 0; i < 8; ++i)
        if (d[i] >= 0) atomicAdd(&cnt_s[d[i] >> NPB_SHIFT], 1);
    __syncthreads();
    if (tid < n_buckets) {
        int c = cnt_s[tid];
        off_s[tid] = c ? atomicAdd(&bkt_cursor[tid], c) : 0;
    }
    __syncthreads();
#pragma unroll
    for (int i = 0; i < 8; ++i) {
        if (d[i] >= 0) {
            int b = d[i] >> NPB_SHIFT;
            int p = atomicAdd(&off_s[b], 1);
            unsigned uq = (unsigned)(uu[i] * 32767.0f + 0.5f);
            rec[p] = ((unsigned long long)(unsigned)d[i] << 32)
                   | (unsigned long long)(((unsigned)s[i] << 15) | uq);
        }
    }
}

// ===== fused: in-LDS mini-CSR + R5 quarter-wave aggregation + MFMA =====
// Block = 64 nodes. Grid swizzle puts a bucket's 8 sub-blocks on ONE XCD
// (blk%8 == bucket%8 == XCD under round-robin dispatch) so the 65KB bucket
// list is fetched into a single L2 (~2MB/XCD/layer).
__global__ __launch_bounds__(512) void k_fused(
        const unsigned* __restrict__ xb_in,   // bf16 rows [n][32] u32 pairs
        const unsigned long long* __restrict__ rec,
        const int* __restrict__ bkt_cursor,
        const short* __restrict__ wb,         // [3][64][64] bf16 (n-major, k-contig)
        const float* __restrict__ bias,
        float* __restrict__ out,              // fp32 out (layer 2) or null
        unsigned short* __restrict__ xb_out,  // bf16 out (layer 1) or null
        int n_nodes, int n_buckets) {
    __shared__ unsigned em_s[RCAP];           // ordered per-node runs
    __shared__ unsigned tmp_em[RCAP];         // staged unordered
    __shared__ unsigned short tmp_d[RCAP];
    __shared__ int cnt_s[64];                 // per-node count (= degree)
    __shared__ int row_s[64];                 // exclusive prefix
    __shared__ int cur_s[64];                 // running cursor
    __shared__ int nm_s;
    __shared__ __align__(16) unsigned gl[64][68];  // bf16 A-tile: w0..31 g0, 32..63 g1
    int tid = threadIdx.x;
    // de-swizzle: blk = c + 8*s + 64*k -> bucket = c + 8*k (pins XCD), sub = s
    int blk = blockIdx.x;
    int b = (blk & 7) + 8 * (blk >> 6);
    int sub = (blk >> 3) & 7;
    if (b >= n_buckets) return;
    int lo = (b << NPB_SHIFT) + (sub << 6);   // node range [lo, lo+64)
    int nrec = bkt_cursor[b] - b * BPAD;
    const unsigned long long* r0 = rec + (size_t)b * BPAD;
    const float inv15 = 1.0f / 32767.0f;

    if (tid < 64) cnt_s[tid] = 0;
    if (tid == 0) nm_s = 0;
    __syncthreads();
    // pass 1: stream bucket list once; filter + stage + hist
    for (int i = tid; i < nrec; i += 512) {
        unsigned long long r = r0[i];
        int rel = (int)(r >> 32) - lo;
        if ((unsigned)rel < 64u) {
            int p = atomicAdd(&nm_s, 1);
            if (p < RCAP) {
                tmp_em[p] = (unsigned)r;
                tmp_d[p] = (unsigned short)rel;
                atomicAdd(&cnt_s[rel], 1);
            }
        }
    }
    __syncthreads();
    // scan 64 counters
    if (tid < 64) row_s[tid] = cnt_s[tid];
    __syncthreads();
    for (int off = 1; off < 64; off <<= 1) {
        int t = (tid < 64 && tid >= off) ? row_s[tid - off] : 0;
        __syncthreads();
        if (tid < 64) row_s[tid] += t;
        __syncthreads();
    }
    if (tid < 64) {
        row_s[tid] -= cnt_s[tid];   // exclusive
        cur_s[tid] = row_s[tid];
    }
    __syncthreads();
    // pass 2 (LDS only): place ordered
    int nm = min(nm_s, RCAP);
    for (int i = tid; i < nm; i += 512) {
        int rel = tmp_d[i];
        int p = atomicAdd(&cur_s[rel], 1);
        em_s[p] = tmp_em[i];
    }
    __syncthreads();

    // --- R5 quarter-wave aggregation (em from LDS, gathers from global) ---
    int qid = tid >> 4;          // 0..31
    int ql = tid & 15;           // channels 4ql..4ql+3
    for (int t = 0; t < 2; ++t) {
        int rel = qid * 2 + t;
        int start = row_s[rel];
        int cnt = cnt_s[rel];
        int end = start + cnt;
        float a0 = 0.f, a1 = 0.f, a2 = 0.f, a3 = 0.f;
        float b0 = 0.f, b1 = 0.f, b2 = 0.f, b3 = 0.f;
        int j = start;
        for (; j + 4 <= end; j += 4) {
            unsigned e[4]; uint2 v[4];
#pragma unroll
            for (int i = 0; i < 4; ++i) e[i] = em_s[j + i];
#pragma unroll
            for (int i = 0; i < 4; ++i)
                v[i] = *(const uint2*)(xb_in + (size_t)(e[i] >> 15) * 32 + 2 * ql);
#pragma unroll
            for (int i = 0; i < 4; ++i) {
                float uu = (float)(e[i] & 0x7fffu) * inv15;
                float wa = 1.0f - uu;
                float c0 = __uint_as_float(v[i].x << 16);
                float c1 = __uint_as_float(v[i].x & 0xffff0000u);
                float c2 = __uint_as_float(v[i].y << 16);
                float c3 = __uint_as_float(v[i].y & 0xffff0000u);
                a0 += wa * c0; a1 += wa * c1; a2 += wa * c2; a3 += wa * c3;
                b0 += uu * c0; b1 += uu * c1; b2 += uu * c2; b3 += uu * c3;
            }
        }
        if (j < end) {   // masked tail (1..3)
            unsigned e[4]; uint2 v[4]; float m[4];
#pragma unroll
            for (int i = 0; i < 4; ++i) {
                int idx = j + i;
                bool ok = idx < end;
                e[i] = em_s[ok ? idx : (end - 1)];
                m[i] = ok ? 1.0f : 0.0f;
            }
#pragma unroll
            for (int i = 0; i < 4; ++i)
                v[i] = *(const uint2*)(xb_in + (size_t)(e[i] >> 15) * 32 + 2 * ql);
#pragma unroll
            for (int i = 0; i < 4; ++i) {
                float uu = (float)(e[i] & 0x7fffu) * inv15;
                float wa = (1.0f - uu) * m[i], wu = uu * m[i];
                float c0 = __uint_as_float(v[i].x << 16);
                float c1 = __uint_as_float(v[i].x & 0xffff0000u);
                float c2 = __uint_as_float(v[i].y << 16);
                float c3 = __uint_as_float(v[i].y & 0xffff0000u);
                a0 += wa * c0; a1 += wa * c1; a2 += wa * c2; a3 += wa * c3;
                b0 += wu * c0; b1 += wu * c1; b2 += wu * c2; b3 += wu * c3;
            }
        }
        float s = 1.0f / fmaxf((float)cnt, 1.0f);
        *(uint2*)&gl[rel][2 * ql] = make_uint2(bfpack(a0 * s, a1 * s), bfpack(a2 * s, a3 * s));
        *(uint2*)&gl[rel][32 + 2 * ql] = make_uint2(bfpack(b0 * s, b1 * s), bfpack(b2 * s, b3 * s));
    }
    __syncthreads();   // gl rows cross waves in the epilogue

    // --- MFMA epilogue (m92-verified layout): 8 waves = 4 tiles x 2 col-halves ---
    int wv = tid >> 6;
    int lane = tid & 63;
    int tile = wv & 3;
    int nthalf = wv >> 2;
    int quad = lane >> 4;
    int m16 = lane & 15;
    int rown = tile * 16 + m16;
    int arow = lo + rown;
    bool rowok = arow < n_nodes;
    const short* gp = (const short*)&gl[rown][0];
    const unsigned* xp = xb_in + (size_t)arow * 32;
    bf16x8 zf = {0, 0, 0, 0, 0, 0, 0, 0};
    bf16x8 aG0[2], aG1[2], aX[2];
#pragma unroll
    for (int kf = 0; kf < 2; ++kf) {
        aG0[kf] = *(const bf16x8*)(gp + kf * 32 + quad * 8);
        aG1[kf] = *(const bf16x8*)(gp + 64 + kf * 32 + quad * 8);
        aX[kf] = rowok ? *(const bf16x8*)(xp + kf * 16 + quad * 4) : zf;
    }
#pragma unroll
    for (int nh = 0; nh < 2; ++nh) {
        int nt = nthalf * 2 + nh;
        f32x4 accv = {0.f, 0.f, 0.f, 0.f};
#pragma unroll
        for (int kf = 0; kf < 2; ++kf) {
            int col = nt * 16 + m16;
            bf16x8 bw0 = *(const bf16x8*)(wb + (col << 6) + kf * 32 + quad * 8);
            bf16x8 bw1 = *(const bf16x8*)(wb + ((64 + col) << 6) + kf * 32 + quad * 8);
            bf16x8 bwR = *(const bf16x8*)(wb + ((128 + col) << 6) + kf * 32 + quad * 8);
            accv = __builtin_amdgcn_mfma_f32_16x16x32_bf16(aG0[kf], bw0, accv, 0, 0, 0);
            accv = __builtin_amdgcn_mfma_f32_16x16x32_bf16(aG1[kf], bw1, accv, 0, 0, 0);
            accv = __builtin_amdgcn_mfma_f32_16x16x32_bf16(aX[kf], bwR, accv, 0, 0, 0);
        }
        float bcol = bias[nt * 16 + m16];
#pragma unroll
        for (int r = 0; r < 4; ++r) {
            int node = lo + tile * 16 + quad * 4 + r;
            if (node < n_nodes) {
                size_t off = (size_t)node * CDIM + nt * 16 + m16;
                float o = accv[r] + bcol;
                if (out) out[off] = o;
                if (xb_out) xb_out[off] = (unsigned short)bf16r(o);
            }
        }
    }
}

extern "C" void kernel_launch(void* const* d_in, const int* in_sizes, int n_in,
                              void* d_out, int out_size, void* d_ws, size_t ws_size,
                              hipStream_t stream) {
    const float* x = (const float*)d_in[0];
    const int* edge_index = (const int*)d_in[1];
    const float* edge_attr = (const float*)d_in[2];
    const float* w1 = (const float*)d_in[3];
    const float* root1 = (const float*)d_in[4];
    const float* b1 = (const float*)d_in[5];
    const float* w2 = (const float*)d_in[6];
    const float* root2 = (const float*)d_in[7];
    const float* b2 = (const float*)d_in[8];

    int n_nodes = in_sizes[0] / CDIM;
    int n_edges = in_sizes[2];
    const int* src = edge_index;
    const int* dst = edge_index + n_edges;

    size_t F = (size_t)n_nodes * CDIM;
    int n_buckets = (n_nodes + BKN - 1) >> NPB_SHIFT;   // 196
    unsigned* xbA = (unsigned*)d_ws;              // F/2 u32: bf16(x)
    unsigned* xbB = xbA + F / 2;                  // F/2 u32: bf16(layer-1 out)
    int* bkt_cursor = (int*)(xbB + F / 2);        // n_buckets
    uintptr_t p = (uintptr_t)(bkt_cursor + n_buckets);
    p = (p + 15) & ~(uintptr_t)15;
    short* wtg = (short*)p;                       // [2][3][64][64] bf16
    p += (size_t)2 * 3 * 4096 * sizeof(short);
    p = (p + 15) & ~(uintptr_t)15;
    unsigned long long* rec = (unsigned long long*)p;  // n_buckets*BPAD u64
    float* out = (float*)d_out;

    int gP = (n_edges + PART_CH - 1) / PART_CH;   // 782
    int gF = 64 * ((n_buckets + 7) / 8);          // 1600 (swizzled; excess blocks exit)

    // ---- build ----
    k_pack<<<2048, 256, 0, stream>>>(x, xbA, F / 2);
    k_prep<<<3, 256, 0, stream>>>(bkt_cursor, n_buckets, w1, root1, w2, root2, wtg);
    k_part<<<gP, 256, 0, stream>>>(src, dst, edge_attr, bkt_cursor, rec, n_edges, n_buckets);

    // ---- layer 1 (bf16 out only) ----
    k_fused<<<gF, 512, 0, stream>>>(xbA, rec, bkt_cursor, wtg, b1,
                                    nullptr, (unsigned short*)xbB, n_nodes, n_buckets);
    // ---- layer 2 (fp32 out) ----
    k_fused<<<gF, 512, 0, stream>>>(xbB, rec, bkt_cursor, wtg + 3 * 4096, b2,
                                    out, nullptr, n_nodes, n_buckets);
}

// Round 10
// 262.991 us; speedup vs baseline: 9.7178x; 1.0324x over previous
//
#include <hip/hip_runtime.h>

#define CDIM 64

typedef __attribute__((ext_vector_type(8))) short bf16x8;
typedef __attribute__((ext_vector_type(4))) float f32x4;

// round-to-nearest-even fp32 -> bf16 (as short)
__device__ __forceinline__ short bf16r(float f) {
    unsigned a = __float_as_uint(f);
    a = (a + 0x7fffu + ((a >> 16) & 1u)) >> 16;
    return (short)a;
}
// pack two fp32 as bf16 pair: first -> bits[15:0], second -> bits[31:16]
__device__ __forceinline__ unsigned bfpack(float lo, float hi) {
    unsigned a = __float_as_uint(lo);
    a = (a + 0x7fffu + ((a >> 16) & 1u)) >> 16;
    unsigned b = __float_as_uint(hi);
    b = (b + 0x7fffu + ((b >> 16) & 1u)) & 0xffff0000u;
    return a | b;
}

// --- pack x (fp32) -> bf16 pairs (u32 per 2 channels) ---
__global__ __launch_bounds__(256) void k_pack(const float* __restrict__ x,
                                              unsigned* __restrict__ xb32, size_t n2) {
    size_t t = (size_t)blockIdx.x * 256 + threadIdx.x;
    size_t stride = (size_t)gridDim.x * 256;
    for (size_t i = t; i < n2; i += stride) {
        float2 v = ((const float2*)x)[i];
        xb32[i] = bfpack(v.x, v.y);
    }
}

#define NPB_SHIFT 9                     // 512 nodes per bucket
#define BKN (1 << NPB_SHIFT)
#define BPAD 10240                      // record slots per bucket (mean 8163, sd 90)
#define PART_CH 2048                    // edges per k_part block
#define RCAP 1536                       // slots per 64-node range (mean 1020, sd 32)

// block 0: init padded bucket cursors; blocks 1,2: pre-transpose weights to
// bf16 n-major (wtg[l][m][n][k]) for direct global B-fragment reads.
__global__ __launch_bounds__(256) void k_prep(int* __restrict__ bkt_cursor, int n_buckets,
                                              const float* __restrict__ w1,
                                              const float* __restrict__ root1,
                                              const float* __restrict__ w2,
                                              const float* __restrict__ root2,
                                              short* __restrict__ wtg) {
    int tid = threadIdx.x;
    if (blockIdx.x == 0) {
        if (tid < n_buckets) bkt_cursor[tid] = tid * BPAD;
        return;
    }
    int l = blockIdx.x - 1;
    const float* s0 = l ? w2 : w1;
    const float* srcs[3] = {s0, s0 + 4096, l ? root2 : root1};
    short* o = wtg + (size_t)l * 3 * 4096;
    for (int i = tid; i < 12288; i += 256) {
        int m = i >> 12, r = i & 4095, k = r >> 6, n = r & 63;  // w row-major [k][n]
        o[(m << 12) + (n << 6) + k] = bf16r(srcs[m][r]);
    }
}

// phase A: bin edges -> bucket-major padded records (d<<32 | s<<15 | u15).
// R9: LDS-staged run writes, ISOLATED this time (R6 bundled it with two other
// changes and the bundle regressed). Mechanism (measured R1): one-at-a-time
// 8B handout stores to 196 runs/block are temporally scattered -> partial-line
// writebacks. Staging bucket-major in LDS + one cooperative sweep makes each
// ~84B run a single wave-coalesced burst.
__global__ __launch_bounds__(256) void k_part(const int* __restrict__ src,
                                              const int* __restrict__ dst,
                                              const float* __restrict__ u,
                                              int* __restrict__ bkt_cursor,
                                              unsigned long long* __restrict__ rec,
                                              int n_edges, int n_buckets) {
    __shared__ int cnt_s[256];
    __shared__ int excl_s[256];
    __shared__ int cur_s[256];
    __shared__ int goff_s[256];
    __shared__ int tot_s;
    __shared__ unsigned long long rec_s[PART_CH];   // 16KB
    __shared__ int tgt_s[PART_CH];                  // 8KB
    int tid = threadIdx.x;
    cnt_s[tid] = 0;
    __syncthreads();
    int e0 = blockIdx.x * PART_CH + tid * 8;
    int d[8], s[8];
    float uu[8];
    if (e0 + 8 <= n_edges) {
        int4 d0 = *(const int4*)(dst + e0), d1 = *(const int4*)(dst + e0 + 4);
        int4 s0 = *(const int4*)(src + e0), s1 = *(const int4*)(src + e0 + 4);
        float4 u0 = *(const float4*)(u + e0), u1 = *(const float4*)(u + e0 + 4);
        d[0]=d0.x; d[1]=d0.y; d[2]=d0.z; d[3]=d0.w; d[4]=d1.x; d[5]=d1.y; d[6]=d1.z; d[7]=d1.w;
        s[0]=s0.x; s[1]=s0.y; s[2]=s0.z; s[3]=s0.w; s[4]=s1.x; s[5]=s1.y; s[6]=s1.z; s[7]=s1.w;
        uu[0]=u0.x; uu[1]=u0.y; uu[2]=u0.z; uu[3]=u0.w; uu[4]=u1.x; uu[5]=u1.y; uu[6]=u1.z; uu[7]=u1.w;
    } else {
#pragma unroll
        for (int i = 0; i < 8; ++i) {
            int e = e0 + i;
            bool ok = e < n_edges;
            d[i] = ok ? dst[e] : -1;
            s[i] = ok ? src[e] : 0;
            uu[i] = ok ? u[e] : 0.f;
        }
    }
#pragma unroll
    for (int i = 0; i < 8; ++i)
        if (d[i] >= 0) atomicAdd(&cnt_s[d[i] >> NPB_SHIFT], 1);
    __syncthreads();
    // inclusive scan of bucket counts
    int c = cnt_s[tid];
    excl_s[tid] = c;
    __syncthreads();
    for (int off = 1; off < 256; off <<= 1) {
        int t = (tid >= off) ? excl_s[tid - off] : 0;
        __syncthreads();
        excl_s[tid] += t;
        __syncthreads();
    }
    int excl = excl_s[tid] - c;
    if (tid == 255) tot_s = excl_s[255];
    __syncthreads();
    excl_s[tid] = excl;
    cur_s[tid] = excl;
    goff_s[tid] = (tid < n_buckets && c) ? atomicAdd(&bkt_cursor[tid], c) : 0;
    __syncthreads();
    // handout into staged LDS (bucket-major) + remember global target
#pragma unroll
    for (int i = 0; i < 8; ++i) {
        if (d[i] >= 0) {
            int b = d[i] >> NPB_SHIFT;
            int p = atomicAdd(&cur_s[b], 1);
            unsigned uq = (unsigned)(uu[i] * 32767.0f + 0.5f);
            rec_s[p] = ((unsigned long long)(unsigned)d[i] << 32)
                     | (unsigned long long)(((unsigned)s[i] << 15) | uq);
            tgt_s[p] = goff_s[b] + (p - excl_s[b]);
        }
    }
    __syncthreads();
    int tot = tot_s;
    for (int i = tid; i < tot; i += 256)
        rec[tgt_s[i]] = rec_s[i];   // consecutive tids -> consecutive targets per run
}

// ===== fused layer kernel =====
// build=1 (layer 1): in-LDS mini-CSR (stream bucket list, filter+stage+hist ->
// scan -> place), DUMP ordered em + row/cnt to global as a side-product, then
// quarter-wave aggregation + MFMA.
// build=0 (layer 2): the graph is identical -> skip the whole build; load
// row/cnt (64 words) and aggregate straight from global em_g (R5-proven
// pattern, 56.5us). The ~15us/layer build cost is paid once, not twice.
__global__ __launch_bounds__(512) void k_fused(
        const unsigned* __restrict__ xb_in,   // bf16 rows [n][32] u32 pairs
        const unsigned long long* __restrict__ rec,
        const int* __restrict__ bkt_cursor,
        const short* __restrict__ wb,         // [3][64][64] bf16 (n-major, k-contig)
        const float* __restrict__ bias,
        float* __restrict__ out,              // fp32 out (layer 2) or null
        unsigned short* __restrict__ xb_out,  // bf16 out (layer 1) or null
        unsigned* __restrict__ em_g,          // [nb*8][RCAP] ordered em dump
        unsigned* __restrict__ rowcnt_g,      // [nb*8][64] row|cnt<<16
        int n_nodes, int n_buckets, int build) {
    __shared__ unsigned em_s[RCAP];           // ordered per-node runs
    __shared__ unsigned tmp_em[RCAP];         // staged unordered
    __shared__ unsigned short tmp_d[RCAP];
    __shared__ int cnt_s[64];                 // per-node count (= degree)
    __shared__ int row_s[64];                 // exclusive prefix
    __shared__ int cur_s[64];                 // running cursor
    __shared__ int nm_s;
    __shared__ __align__(16) unsigned gl[64][68];  // bf16 A-tile: w0..31 g0, 32..63 g1
    int tid = threadIdx.x;
    // de-swizzle: blk = c + 8*s + 64*k -> bucket = c + 8*k (pins XCD), sub = s
    int blk = blockIdx.x;
    int b = (blk & 7) + 8 * (blk >> 6);
    int sub = (blk >> 3) & 7;
    if (b >= n_buckets) return;
    int lo = (b << NPB_SHIFT) + (sub << 6);   // node range [lo, lo+64)
    int region = ((b << 3) + sub) * RCAP;
    const float inv15 = 1.0f / 32767.0f;

    if (build) {
        int nrec = bkt_cursor[b] - b * BPAD;
        const unsigned long long* r0 = rec + (size_t)b * BPAD;
        if (tid < 64) cnt_s[tid] = 0;
        if (tid == 0) nm_s = 0;
        __syncthreads();
        // pass 1: stream bucket list once; filter + stage + hist
        for (int i = tid; i < nrec; i += 512) {
            unsigned long long r = r0[i];
            int rel = (int)(r >> 32) - lo;
            if ((unsigned)rel < 64u) {
                int p = atomicAdd(&nm_s, 1);
                if (p < RCAP) {
                    tmp_em[p] = (unsigned)r;
                    tmp_d[p] = (unsigned short)rel;
                    atomicAdd(&cnt_s[rel], 1);
                }
            }
        }
        __syncthreads();
        // scan 64 counters
        if (tid < 64) row_s[tid] = cnt_s[tid];
        __syncthreads();
        for (int off = 1; off < 64; off <<= 1) {
            int t = (tid < 64 && tid >= off) ? row_s[tid - off] : 0;
            __syncthreads();
            if (tid < 64) row_s[tid] += t;
            __syncthreads();
        }
        if (tid < 64) {
            row_s[tid] -= cnt_s[tid];   // exclusive
            cur_s[tid] = row_s[tid];
        }
        __syncthreads();
        // pass 2 (LDS only): place ordered
        int nm = min(nm_s, RCAP);
        for (int i = tid; i < nm; i += 512) {
            int rel = tmp_d[i];
            int p = atomicAdd(&cur_s[rel], 1);
            em_s[p] = tmp_em[i];
        }
        __syncthreads();
        // dump side-product for layer 2 (reads stable em_s/row_s/cnt_s)
        if (tid < 64)
            rowcnt_g[((b << 3) + sub) * 64 + tid] =
                (unsigned)row_s[tid] | ((unsigned)cnt_s[tid] << 16);
        for (int i = tid; i < nm; i += 512) em_g[region + i] = em_s[i];
    } else {
        if (tid < 64) {
            unsigned rc = rowcnt_g[((b << 3) + sub) * 64 + tid];
            row_s[tid] = (int)(rc & 0xffffu);
            cnt_s[tid] = (int)(rc >> 16);
        }
        __syncthreads();
    }

    // --- quarter-wave aggregation (em from LDS in build mode, global else) ---
    const unsigned* em = build ? (const unsigned*)&em_s[0] : (em_g + region);
    int qid = tid >> 4;          // 0..31
    int ql = tid & 15;           // channels 4ql..4ql+3
    for (int t = 0; t < 2; ++t) {
        int rel = qid * 2 + t;
        int start = row_s[rel];
        int cnt = cnt_s[rel];
        int end = start + cnt;
        float a0 = 0.f, a1 = 0.f, a2 = 0.f, a3 = 0.f;
        float b0 = 0.f, b1 = 0.f, b2 = 0.f, b3 = 0.f;
        int j = start;
        for (; j + 4 <= end; j += 4) {
            unsigned e[4]; uint2 v[4];
#pragma unroll
            for (int i = 0; i < 4; ++i) e[i] = em[j + i];
#pragma unroll
            for (int i = 0; i < 4; ++i)
                v[i] = *(const uint2*)(xb_in + (size_t)(e[i] >> 15) * 32 + 2 * ql);
#pragma unroll
            for (int i = 0; i < 4; ++i) {
                float uu = (float)(e[i] & 0x7fffu) * inv15;
                float wa = 1.0f - uu;
                float c0 = __uint_as_float(v[i].x << 16);
                float c1 = __uint_as_float(v[i].x & 0xffff0000u);
                float c2 = __uint_as_float(v[i].y << 16);
                float c3 = __uint_as_float(v[i].y & 0xffff0000u);
                a0 += wa * c0; a1 += wa * c1; a2 += wa * c2; a3 += wa * c3;
                b0 += uu * c0; b1 += uu * c1; b2 += uu * c2; b3 += uu * c3;
            }
        }
        if (j < end) {   // masked tail (1..3)
            unsigned e[4]; uint2 v[4]; float m[4];
#pragma unroll
            for (int i = 0; i < 4; ++i) {
                int idx = j + i;
                bool ok = idx < end;
                e[i] = em[ok ? idx : (end - 1)];
                m[i] = ok ? 1.0f : 0.0f;
            }
#pragma unroll
            for (int i = 0; i < 4; ++i)
                v[i] = *(const uint2*)(xb_in + (size_t)(e[i] >> 15) * 32 + 2 * ql);
#pragma unroll
            for (int i = 0; i < 4; ++i) {
                float uu = (float)(e[i] & 0x7fffu) * inv15;
                float wa = (1.0f - uu) * m[i], wu = uu * m[i];
                float c0 = __uint_as_float(v[i].x << 16);
                float c1 = __uint_as_float(v[i].x & 0xffff0000u);
                float c2 = __uint_as_float(v[i].y << 16);
                float c3 = __uint_as_float(v[i].y & 0xffff0000u);
                a0 += wa * c0; a1 += wa * c1; a2 += wa * c2; a3 += wa * c3;
                b0 += wu * c0; b1 += wu * c1; b2 += wu * c2; b3 += wu * c3;
            }
        }
        float s = 1.0f / fmaxf((float)cnt, 1.0f);
        *(uint2*)&gl[rel][2 * ql] = make_uint2(bfpack(a0 * s, a1 * s), bfpack(a2 * s, a3 * s));
        *(uint2*)&gl[rel][32 + 2 * ql] = make_uint2(bfpack(b0 * s, b1 * s), bfpack(b2 * s, b3 * s));
    }
    __syncthreads();   // gl rows cross waves in the epilogue

    // --- MFMA epilogue (m92-verified layout): 8 waves = 4 tiles x 2 col-halves ---
    int wv = tid >> 6;
    int lane = tid & 63;
    int tile = wv & 3;
    int nthalf = wv >> 2;
    int quad = lane >> 4;
    int m16 = lane & 15;
    int rown = tile * 16 + m16;
    int arow = lo + rown;
    bool rowok = arow < n_nodes;
    const short* gp = (const short*)&gl[rown][0];
    const unsigned* xp = xb_in + (size_t)arow * 32;
    bf16x8 zf = {0, 0, 0, 0, 0, 0, 0, 0};
    bf16x8 aG0[2], aG1[2], aX[2];
#pragma unroll
    for (int kf = 0; kf < 2; ++kf) {
        aG0[kf] = *(const bf16x8*)(gp + kf * 32 + quad * 8);
        aG1[kf] = *(const bf16x8*)(gp + 64 + kf * 32 + quad * 8);
        aX[kf] = rowok ? *(const bf16x8*)(xp + kf * 16 + quad * 4) : zf;
    }
#pragma unroll
    for (int nh = 0; nh < 2; ++nh) {
        int nt = nthalf * 2 + nh;
        f32x4 accv = {0.f, 0.f, 0.f, 0.f};
#pragma unroll
        for (int kf = 0; kf < 2; ++kf) {
            int col = nt * 16 + m16;
            bf16x8 bw0 = *(const bf16x8*)(wb + (col << 6) + kf * 32 + quad * 8);
            bf16x8 bw1 = *(const bf16x8*)(wb + ((64 + col) << 6) + kf * 32 + quad * 8);
            bf16x8 bwR = *(const bf16x8*)(wb + ((128 + col) << 6) + kf * 32 + quad * 8);
            accv = __builtin_amdgcn_mfma_f32_16x16x32_bf16(aG0[kf], bw0, accv, 0, 0, 0);
            accv = __builtin_amdgcn_mfma_f32_16x16x32_bf16(aG1[kf], bw1, accv, 0, 0, 0);
            accv = __builtin_amdgcn_mfma_f32_16x16x32_bf16(aX[kf], bwR, accv, 0, 0, 0);
        }
        float bcol = bias[nt * 16 + m16];
#pragma unroll
        for (int r = 0; r < 4; ++r) {
            int node = lo + tile * 16 + quad * 4 + r;
            if (node < n_nodes) {
                size_t off = (size_t)node * CDIM + nt * 16 + m16;
                float o = accv[r] + bcol;
                if (out) out[off] = o;
                if (xb_out) xb_out[off] = (unsigned short)bf16r(o);
            }
        }
    }
}

extern "C" void kernel_launch(void* const* d_in, const int* in_sizes, int n_in,
                              void* d_out, int out_size, void* d_ws, size_t ws_size,
                              hipStream_t stream) {
    const float* x = (const float*)d_in[0];
    const int* edge_index = (const int*)d_in[1];
    const float* edge_attr = (const float*)d_in[2];
    const float* w1 = (const float*)d_in[3];
    const float* root1 = (const float*)d_in[4];
    const float* b1 = (const float*)d_in[5];
    const float* w2 = (const float*)d_in[6];
    const float* root2 = (const float*)d_in[7];
    const float* b2 = (const float*)d_in[8];

    int n_nodes = in_sizes[0] / CDIM;
    int n_edges = in_sizes[2];
    const int* src = edge_index;
    const int* dst = edge_index + n_edges;

    size_t F = (size_t)n_nodes * CDIM;
    int n_buckets = (n_nodes + BKN - 1) >> NPB_SHIFT;   // 196
    int nb8 = n_buckets * 8;                            // 1568 sub-ranges
    unsigned* xbA = (unsigned*)d_ws;              // F/2 u32: bf16(x)
    unsigned* xbB = xbA + F / 2;                  // F/2 u32: bf16(layer-1 out)
    int* bkt_cursor = (int*)(xbB + F / 2);        // n_buckets
    uintptr_t p = (uintptr_t)(bkt_cursor + n_buckets);
    p = (p + 15) & ~(uintptr_t)15;
    short* wtg = (short*)p;                       // [2][3][64][64] bf16
    p += (size_t)2 * 3 * 4096 * sizeof(short);
    p = (p + 15) & ~(uintptr_t)15;
    unsigned* em_g = (unsigned*)p;                // nb8*RCAP u32 (ordered em dump)
    p += (size_t)nb8 * RCAP * sizeof(unsigned);
    unsigned* rowcnt_g = (unsigned*)p;            // nb8*64 u32
    p += (size_t)nb8 * 64 * sizeof(unsigned);
    p = (p + 15) & ~(uintptr_t)15;
    unsigned long long* rec = (unsigned long long*)p;  // n_buckets*BPAD u64
    float* out = (float*)d_out;

    int gP = (n_edges + PART_CH - 1) / PART_CH;   // 782
    int gF = 64 * ((n_buckets + 7) / 8);          // 1600 (swizzled; excess exit)

    // ---- build ----
    k_pack<<<2048, 256, 0, stream>>>(x, xbA, F / 2);
    k_prep<<<3, 256, 0, stream>>>(bkt_cursor, n_buckets, w1, root1, w2, root2, wtg);
    k_part<<<gP, 256, 0, stream>>>(src, dst, edge_attr, bkt_cursor, rec, n_edges, n_buckets);

    // ---- layer 1 (build mini-CSR + dump; bf16 out) ----
    k_fused<<<gF, 512, 0, stream>>>(xbA, rec, bkt_cursor, wtg, b1,
                                    nullptr, (unsigned short*)xbB,
                                    em_g, rowcnt_g, n_nodes, n_buckets, 1);
    // ---- layer 2 (reuse dumped CSR; fp32 out) ----
    k_fused<<<gF, 512, 0, stream>>>(xbB, rec, bkt_cursor, wtg + 3 * 4096, b2,
                                    out, nullptr,
                                    em_g, rowcnt_g, n_nodes, n_buckets, 0);
}